// Round 14
// baseline (301.052 us; speedup 1.0000x reference)
//
#include <hip/hip_runtime.h>
#include <hip/hip_bf16.h>

// Problem constants
#define NN 10000
#define EE 160000
#define IN_DIM 128
#define HID 128
#define HEADS 8
#define F1 (HEADS*HID)   // 1024
#define INT_DIM 512
#define OUT_DIM 3
#define MPAD 10112       // 79 * 128

typedef __attribute__((ext_vector_type(4))) float f32x4;
typedef __attribute__((ext_vector_type(8))) _Float16 half8;
typedef __attribute__((ext_vector_type(4))) _Float16 half4;
typedef __attribute__((ext_vector_type(2))) _Float16 half2v;

// wave-local LDS fence: wait all this wave's DS ops, and pin program order
#define WAVE_SYNC() do { asm volatile("s_waitcnt lgkmcnt(0)" ::: "memory"); \
                         __builtin_amdgcn_sched_barrier(0); } while(0)

// ---------------- CSR build ----------------
__global__ __launch_bounds__(256) void count_kernel(const int* __restrict__ dst, int E, int* __restrict__ cnt){
    int e = blockIdx.x*256 + threadIdx.x;
    if(e < E) atomicAdd(&cnt[dst[e]], 1);
}

__global__ __launch_bounds__(256) void scan_kernel(const int* __restrict__ cnt, int* __restrict__ rowp,
                                                   int* __restrict__ cursor, int n){
    __shared__ int sh[256];
    __shared__ int stotal;
    int t = threadIdx.x;
    if(t==0) stotal = 0;
    __syncthreads();
    for(int base=0; base<n; base+=256){
        int i = base + t;
        int v = (i<n) ? cnt[i] : 0;
        sh[t] = v;
        __syncthreads();
        #pragma unroll
        for(int off=1; off<256; off<<=1){
            int add = (t>=off) ? sh[t-off] : 0;
            __syncthreads();
            sh[t] += add;
            __syncthreads();
        }
        int excl = sh[t] - v;
        if(i<n){ rowp[i] = stotal + excl; cursor[i] = stotal + excl; }
        int chunk_total = sh[255];
        __syncthreads();
        if(t==0) stotal += chunk_total;
        __syncthreads();
    }
    if(t==0) rowp[n] = stotal;
}

__global__ __launch_bounds__(256) void fill_kernel(const int* __restrict__ src, const int* __restrict__ dst,
                                                   int E, int* __restrict__ cursor, int* __restrict__ colsrc){
    int e = blockIdx.x*256 + threadIdx.x;
    if(e < E){
        int d = dst[e];
        int pos = atomicAdd(&cursor[d], 1);
        colsrc[pos] = src[e];
    }
}

// ---------------- transpose weights to fp16: B[K,N] fp32 -> T [N,K] fp16 ----------------
__global__ __launch_bounds__(256) void splitT16_kernel(const float* __restrict__ B, _Float16* __restrict__ T,
                                                       int K, int N){
    __shared__ float tile[32][33];
    const int tx = threadIdx.x & 31, ty = threadIdx.x >> 5;   // 32 x 8
    const int n0 = blockIdx.x * 32, k0 = blockIdx.y * 32;
    #pragma unroll
    for(int i = 0; i < 32; i += 8)
        tile[ty + i][tx] = B[(size_t)(k0 + ty + i) * N + n0 + tx];
    __syncthreads();
    #pragma unroll
    for(int i = 0; i < 32; i += 8){
        int n = ty + i;
        T[(size_t)(n0 + n) * K + k0 + tx] = (_Float16)tile[tx][n];
    }
}

// ---------------- x fp32 -> fp16 ----------------
__global__ __launch_bounds__(256) void x16_kernel(const float* __restrict__ x, _Float16* __restrict__ x16, int n4){
    int i = blockIdx.x*256 + threadIdx.x;
    if(i >= n4) return;
    float4 v = ((const float4*)x)[i];
    half4 o = { (_Float16)v.x, (_Float16)v.y, (_Float16)v.z, (_Float16)v.w };
    ((half4*)x16)[i] = o;
}

// ---------------- aw1[j][k] = sum_c a[j][c] * W1[k, hj*128+c]  (j<8: a_src, j>=8: a_dst) ----------------
__global__ __launch_bounds__(256) void aw1_kernel(const float* __restrict__ W1,
                                                  const float* __restrict__ a_src,
                                                  const float* __restrict__ a_dst,
                                                  float* __restrict__ aw){
    int idx = blockIdx.x*256 + threadIdx.x;
    if(idx >= 16*IN_DIM) return;
    int j = idx >> 7, k = idx & 127;
    int hj = j & 7;
    const float* av = (j < 8 ? a_src : a_dst) + hj*HID;
    const float* wr = W1 + (size_t)k*F1 + hj*HID;
    float s = 0.f;
    #pragma unroll 4
    for(int c = 0; c < HID; c++) s += av[c] * wr[c];
    aw[idx] = s;
}

// ---------------- alpha1[n, j] = x[n,:] @ aw[j,:]  -> asrc/adst [NN,8] ----------------
__global__ __launch_bounds__(256) void alpha1_kernel(const float* __restrict__ x,
                                                     const float* __restrict__ aw,
                                                     float* __restrict__ asrc, float* __restrict__ adst){
    __shared__ float xs[16][128];
    __shared__ float aws[16][128];
    int t = threadIdx.x;
    int nb = blockIdx.x * 16;
    for(int i = t; i < 16*128; i += 256){
        xs[i >> 7][i & 127] = x[(size_t)nb*128 + i];
        aws[i >> 7][i & 127] = aw[i];
    }
    __syncthreads();
    int nl = t >> 4, j = t & 15;
    float s = 0.f;
    #pragma unroll 4
    for(int c = 0; c < 128; c++) s += xs[nl][c] * aws[j][c];
    int node = nb + nl;
    if(j < 8) asrc[node*8 + j] = s;
    else      adst[node*8 + (j-8)] = s;
}

// ---------------- agg1: per-head softmax-agg of fp16 x; 4 nodes/block, 1 wave/node; emits fp16 ----------------
__global__ __launch_bounds__(256) void agg1_kernel(const _Float16* __restrict__ x16,
                                                   const float* __restrict__ asrc,
                                                   const float* __restrict__ adst,
                                                   const int* __restrict__ rowp,
                                                   const int* __restrict__ colsrc,
                                                   _Float16* __restrict__ oa){
    const int w = threadIdx.x >> 6, l = threadIdx.x & 63;
    const int node = blockIdx.x*4 + w;
    __shared__ float sh_ee[4][64][8];
    int beg = rowp[node], end = rowp[node+1];
    float rd = adst[node*8 + (l & 7)];
    float acc0[8], acc1[8];
    #pragma unroll
    for(int h=0;h<8;h++){ acc0[h]=0.f; acc1[h]=0.f; }
    float dpart = 0.f;
    for(int base=beg; base<end; base+=64){
        int clen = min(64, end-base);
        WAVE_SYNC();                        // prior chunk's ee reads complete
        int sreg = (l < clen) ? colsrc[base + l] : 0;
        for(int it=l; it<clen*8; it+=64){
            int j = it >> 3;
            int s = colsrc[base + j];
            float e = asrc[s*8 + (l & 7)] + rd;
            e = (e > 0.f) ? e : 0.2f*e;
            float ee = expf(e);
            sh_ee[w][j][l & 7] = ee;
            dpart += ee;
        }
        WAVE_SYNC();                        // ee visible wave-wide
        #pragma unroll 2
        for(int j=0;j<clen;j++){
            int s = __shfl(sreg, j);
            half2v xv = ((const half2v*)(x16 + (size_t)s*128))[l];
            float x0 = (float)xv[0], x1 = (float)xv[1];
            #pragma unroll
            for(int h=0;h<8;h++){
                float wt = sh_ee[w][j][h];
                acc0[h] += wt * x0;
                acc1[h] += wt * x1;
            }
        }
    }
    dpart += __shfl_xor(dpart, 8);
    dpart += __shfl_xor(dpart, 16);
    dpart += __shfl_xor(dpart, 32);         // lane l holds denom for head l&7
    #pragma unroll
    for(int h=0;h<8;h++){
        float dn = __shfl(dpart, h) + 1e-16f;
        half2v o = { (_Float16)(acc0[h]/dn), (_Float16)(acc1[h]/dn) };
        *(half2v*)(oa + (size_t)node*F1 + h*128 + 2*l) = o;
    }
}

// ---------------- agg2: head-partitioned gather; 16-lane group per edge, half8 per lane ----------------
// Block = (node-group, head); head = blockIdx&7 (round-robin XCD -> per-XCD 2.59 MB slice, L2-resident).
// Wave processes 4 edges at once: group g (lanes 16g..16g+15) handles edge j0+g; lane loads 16 B.
__global__ __launch_bounds__(256) void agg2_kernel(const _Float16* __restrict__ hbuf,
                                                   const float* __restrict__ asrc,
                                                   const float* __restrict__ adst,
                                                   const int* __restrict__ rowp,
                                                   const int* __restrict__ colsrc,
                                                   const float* __restrict__ bias,
                                                   _Float16* __restrict__ oa){
    const int w = threadIdx.x >> 6, l = threadIdx.x & 63;
    const int h = blockIdx.x & 7;
    const int node = (blockIdx.x >> 3)*4 + w;
    const int g = l >> 4, i = l & 15;    // group g -> edge j0+g; lane i -> features 8i..8i+7
    int beg = rowp[node], end = rowp[node+1];
    float rd = adst[node*8 + h];
    float acc[8];
    #pragma unroll
    for(int k=0;k<8;k++) acc[k]=0.f;
    float dpart = 0.f;
    const _Float16* hb = hbuf + h*128 + 8*i;
    for(int base=beg; base<end; base+=64){
        int clen = min(64, end-base);
        int sreg = 0; float eereg = 0.f;
        if(l < clen){
            sreg = colsrc[base + l];
            float e = asrc[sreg*8 + h] + rd;
            e = (e > 0.f) ? e : 0.2f*e;
            eereg = expf(e);
            dpart += eereg;
        }
        int cpad = (clen + 3) & ~3;
        // 2-deep pipeline over 4-edge groups
        int s0 = __shfl(sreg, g);
        float w0 = __shfl(eereg, g);
        half8 v0 = *(const half8*)(hb + (size_t)s0*F1);
        #pragma unroll 1
        for(int j0=0; j0<cpad; j0+=4){
            half8 nv; float nw = 0.f;
            const bool more = (j0+4 < cpad);
            if(more){
                int ns = __shfl(sreg, j0+4+g);
                nw = __shfl(eereg, j0+4+g);
                nv = *(const half8*)(hb + (size_t)ns*F1);
            }
            #pragma unroll
            for(int k=0;k<8;k++) acc[k] += w0 * (float)v0[k];
            if(more){ v0 = nv; w0 = nw; }
        }
    }
    // reduce partial sums across the 4 edge-groups
    #pragma unroll
    for(int k=0;k<8;k++){
        acc[k] += __shfl_xor(acc[k], 16);
        acc[k] += __shfl_xor(acc[k], 32);
    }
    // softmax denom over all 64 lanes
    #pragma unroll
    for(int off=1; off<64; off<<=1) dpart += __shfl_xor(dpart, off);
    float dn = dpart + 1e-16f;
    if(g == 0){
        const int f = h*128 + 8*i;
        float4 b0 = *(const float4*)(bias + f);
        float4 b1 = *(const float4*)(bias + f + 4);
        float bb[8] = {b0.x,b0.y,b0.z,b0.w, b1.x,b1.y,b1.z,b1.w};
        half8 o;
        #pragma unroll
        for(int k=0;k<8;k++)
            o[k] = (_Float16)fmaxf(acc[k]/dn + bb[k], 0.f);
        *(half8*)(oa + (size_t)node*F1 + f) = o;
    }
}

// ---------------- agg3: chunk-partitioned gather (H=1); 16-lane group per edge, half8 per lane ----------------
__global__ __launch_bounds__(256) void agg3_kernel(const _Float16* __restrict__ hbuf,
                                                   const float* __restrict__ asrc,
                                                   const float* __restrict__ adst,
                                                   const int* __restrict__ rowp,
                                                   const int* __restrict__ colsrc,
                                                   const float* __restrict__ bias,
                                                   _Float16* __restrict__ oa){
    const int w = threadIdx.x >> 6, l = threadIdx.x & 63;
    const int i7 = blockIdx.x & 7;
    const int chunk = i7 & 3, sub = i7 >> 2;
    const int node = ((blockIdx.x >> 3)*2 + sub)*4 + w;
    const int g = l >> 4, i = l & 15;
    int beg = rowp[node], end = rowp[node+1];
    float rd = adst[node];
    float acc[8];
    #pragma unroll
    for(int k=0;k<8;k++) acc[k]=0.f;
    float dpart = 0.f;
    const _Float16* hb = hbuf + chunk*128 + 8*i;
    for(int base=beg; base<end; base+=64){
        int clen = min(64, end-base);
        int sreg = 0; float eereg = 0.f;
        if(l < clen){
            sreg = colsrc[base + l];
            float e = asrc[sreg] + rd;
            e = (e > 0.f) ? e : 0.2f*e;
            eereg = expf(e);
            dpart += eereg;
        }
        int cpad = (clen + 3) & ~3;
        int s0 = __shfl(sreg, g);
        float w0 = __shfl(eereg, g);
        half8 v0 = *(const half8*)(hb + (size_t)s0*INT_DIM);
        #pragma unroll 1
        for(int j0=0; j0<cpad; j0+=4){
            half8 nv; float nw = 0.f;
            const bool more = (j0+4 < cpad);
            if(more){
                int ns = __shfl(sreg, j0+4+g);
                nw = __shfl(eereg, j0+4+g);
                nv = *(const half8*)(hb + (size_t)ns*INT_DIM);
            }
            #pragma unroll
            for(int k=0;k<8;k++) acc[k] += w0 * (float)v0[k];
            if(more){ v0 = nv; w0 = nw; }
        }
    }
    #pragma unroll
    for(int k=0;k<8;k++){
        acc[k] += __shfl_xor(acc[k], 16);
        acc[k] += __shfl_xor(acc[k], 32);
    }
    #pragma unroll
    for(int off=1; off<64; off<<=1) dpart += __shfl_xor(dpart, off);
    float dn = dpart + 1e-16f;
    if(g == 0){
        const int f = chunk*128 + 8*i;
        float4 b0 = *(const float4*)(bias + f);
        float4 b1 = *(const float4*)(bias + f + 4);
        float bb[8] = {b0.x,b0.y,b0.z,b0.w, b1.x,b1.y,b1.z,b1.w};
        half8 o;
        #pragma unroll
        for(int k=0;k<8;k++)
            o[k] = (_Float16)fmaxf(acc[k]/dn + bb[k], 0.f);
        *(half8*)(oa + (size_t)node*INT_DIM + f) = o;
    }
}

// ---------------- single-pass fp16 MFMA GEMM, 8 waves (2x4), 128x128 tile, dbuf 2-phase ----------------
template<int FUSE>
__global__ __launch_bounds__(512, 4) void mfma16_gemm_kernel(
    const _Float16* __restrict__ A, int lda, int za,
    const _Float16* __restrict__ B, int ldb, int zb,
    const float* __restrict__ bias, _Float16* __restrict__ O,
    int ldc, int zc, int K, int gx)
{
    __shared__ _Float16 lA[2][128*32];   // 8 KB per buffer
    __shared__ _Float16 lB[2][128*32];
    const int tid  = threadIdx.x;
    const int lane = tid & 63;
    const int w    = tid >> 6;      // 0..7
    const int wm   = w >> 2;        // 0..1 (row half)
    const int wn   = w & 3;         // 0..3 (col quarter)
    const int z    = blockIdx.z;

    // XCD-bijective swizzle
    const int nwg = gridDim.x;
    const int q = nwg >> 3, r = nwg & 7;
    const int xcd = blockIdx.x & 7, idx = blockIdx.x >> 3;
    const int wgid = (xcd < r ? xcd*(q+1) : r*(q+1) + (xcd-r)*q) + idx;
    const int row0 = (wgid / gx) * 128, col0 = (wgid % gx) * 128;

    f32x4 acc[4][2];
    #pragma unroll
    for(int i=0;i<4;i++)
        #pragma unroll
        for(int j=0;j<2;j++) acc[i][j] = (f32x4){0.f,0.f,0.f,0.f};

    // staging: 512 lanes cover 128 rows x 4 slots of 16B; LDS slot written = tid&3
    const int rr1 = tid >> 2;                        // 0..127
    const int ss1 = (tid & 3) ^ ((rr1 >> 1) & 3);    // swizzled global slot
    const size_t aoff = (size_t)(row0 + rr1) * lda + (size_t)z*za + ss1 * 8;
    const size_t boff = (size_t)(col0 + rr1) * ldb + (size_t)z*zb + ss1 * 8;

    typedef __attribute__((address_space(3))) char lds_char;
    lds_char* dA = (lds_char*)(&lA[0][0]) + w*1024;
    lds_char* dB = (lds_char*)(&lB[0][0]) + w*1024;

    int arow[4], brow[2];
    const int slotx = ((lane >> 4) ^ ((lane >> 1) & 3)) << 4;
    #pragma unroll
    for(int i=0;i<4;i++)
        arow[i] = (wm*64 + i*16 + (lane & 15)) * 64 + slotx;
    #pragma unroll
    for(int j=0;j<2;j++)
        brow[j] = (wn*32 + j*16 + (lane & 15)) * 64 + slotx;

    #define GLDS(src, dst) __builtin_amdgcn_global_load_lds( \
        (__attribute__((address_space(1))) void*)(src), \
        (__attribute__((address_space(3))) void*)(dst), 16, 0, 0)
    GLDS(A + aoff, dA);
    GLDS(B + boff, dB);
    __syncthreads();

    #pragma unroll 1
    for(int k0 = 0, kb = 0; k0 < K; k0 += 32, kb ^= 1){
        if(k0 + 32 < K){
            const int nb = kb ^ 1;
            GLDS(A + aoff + k0 + 32, dA + nb*8192);
            GLDS(B + boff + k0 + 32, dB + nb*8192);
        }
        const char* pA = (const char*)(&lA[0][0]) + kb*8192;
        const char* pB = (const char*)(&lB[0][0]) + kb*8192;
        half8 af[4];
        #pragma unroll
        for(int i=0;i<4;i++) af[i] = *(const half8*)(pA + arow[i]);
        #pragma unroll
        for(int j=0;j<2;j++){
            half8 bf = *(const half8*)(pB + brow[j]);
            #pragma unroll
            for(int i=0;i<4;i++)
                acc[i][j] = __builtin_amdgcn_mfma_f32_16x16x32_f16(af[i], bf, acc[i][j], 0, 0, 0);
        }
        __syncthreads();
    }
    #undef GLDS

    // epilogue: C/D layout col=lane&15, row=(lane>>4)*4+reg
    #pragma unroll
    for(int i=0;i<4;i++){
        const int rr = row0 + wm*64 + i*16 + ((lane >> 4) << 2);
        #pragma unroll
        for(int j=0;j<2;j++){
            const int gc = z*zc + col0 + wn*32 + j*16 + (lane & 15);
            float b = FUSE ? bias[gc] : 0.f;
            #pragma unroll
            for(int rg=0;rg<4;rg++){
                float v = acc[i][j][rg];
                if(FUSE) v = fmaxf(v + b, 0.f);
                O[(size_t)(rr + rg) * ldc + gc] = (_Float16)v;
            }
        }
    }
}

// ---------------- alpha from fp16 h: H=8, C=128 ----------------
__global__ __launch_bounds__(128) void alpha16_h8_kernel(const _Float16* __restrict__ hbuf,
                                                         const float* __restrict__ a_src,
                                                         const float* __restrict__ a_dst,
                                                         float* __restrict__ asrc, float* __restrict__ adst){
    int node = blockIdx.x;
    int t = threadIdx.x;          // 128 threads; features 8t..8t+7, head t>>4
    half8 v = ((const half8*)(hbuf + (size_t)node*F1))[t];
    const float4* ap = (const float4*)(a_src + 8*t);
    const float4* dp = (const float4*)(a_dst + 8*t);
    float4 a0 = ap[0], a1 = ap[1];
    float4 d0 = dp[0], d1 = dp[1];
    float av[8] = {a0.x,a0.y,a0.z,a0.w, a1.x,a1.y,a1.z,a1.w};
    float dv[8] = {d0.x,d0.y,d0.z,d0.w, d1.x,d1.y,d1.z,d1.w};
    float ps = 0.f, pd = 0.f;
    #pragma unroll
    for(int k=0;k<8;k++){
        float f = (float)v[k];
        ps += f * av[k];
        pd += f * dv[k];
    }
    #pragma unroll
    for(int off=8; off; off>>=1){ ps += __shfl_down(ps, off); pd += __shfl_down(pd, off); }
    if((t & 15) == 0){
        asrc[(size_t)node*8 + (t>>4)] = ps;
        adst[(size_t)node*8 + (t>>4)] = pd;
    }
}

// ---------------- alpha from fp16 h: H=1, C=512 ----------------
__global__ __launch_bounds__(128) void alpha16_h1_kernel(const _Float16* __restrict__ hbuf,
                                                         const float* __restrict__ a_src,
                                                         const float* __restrict__ a_dst,
                                                         float* __restrict__ asrc, float* __restrict__ adst){
    int node = blockIdx.x;
    int t = threadIdx.x;          // 128 threads; features 4t..4t+3
    half4 v = ((const half4*)(hbuf + (size_t)node*INT_DIM))[t];
    float4 a = ((const float4*)a_src)[t];
    float4 d = ((const float4*)a_dst)[t];
    float ps = (float)v[0]*a.x + (float)v[1]*a.y + (float)v[2]*a.z + (float)v[3]*a.w;
    float pd = (float)v[0]*d.x + (float)v[1]*d.y + (float)v[2]*d.z + (float)v[3]*d.w;
    #pragma unroll
    for(int off=32; off; off>>=1){ ps += __shfl_down(ps, off); pd += __shfl_down(pd, off); }
    __shared__ float shs[2], shd[2];
    int wv = t >> 6;
    if((t & 63) == 0){ shs[wv] = ps; shd[wv] = pd; }
    __syncthreads();
    if(t == 0){
        asrc[node] = shs[0] + shs[1];
        adst[node] = shd[0] + shd[1];
    }
}

// ---------------- classifier: out[n,3] = h16[n,:512] @ Wc + bc ----------------
__global__ __launch_bounds__(256) void cls16_kernel(const _Float16* __restrict__ h, const float* __restrict__ Wc,
                                                    const float* __restrict__ bc, float* __restrict__ out, int n){
    int node = blockIdx.x*4 + (threadIdx.x >> 6);
    int lane = threadIdx.x & 63;
    if(node >= n) return;
    half8 v = ((const half8*)(h + (size_t)node*INT_DIM))[lane];  // features 8l..8l+7
    float s0=0.f, s1=0.f, s2=0.f;
    #pragma unroll
    for(int k=0;k<8;k++){
        float f = (float)v[k];
        const float* wr = Wc + (8*lane + k)*3;
        s0 += f * wr[0];
        s1 += f * wr[1];
        s2 += f * wr[2];
    }
    #pragma unroll
    for(int off=32; off; off>>=1){
        s0 += __shfl_down(s0, off);
        s1 += __shfl_down(s1, off);
        s2 += __shfl_down(s2, off);
    }
    if(lane==0){
        out[(size_t)node*3+0] = s0 + bc[0];
        out[(size_t)node*3+1] = s1 + bc[1];
        out[(size_t)node*3+2] = s2 + bc[2];
    }
}

extern "C" void kernel_launch(void* const* d_in, const int* in_sizes, int n_in,
                              void* d_out, int out_size, void* d_ws, size_t ws_size,
                              hipStream_t stream){
    const float* x      = (const float*)d_in[0];
    const int*   ei     = (const int*)d_in[1];
    const float* W1     = (const float*)d_in[2];
    const float* a_src1 = (const float*)d_in[3];
    const float* a_dst1 = (const float*)d_in[4];
    const float* b1     = (const float*)d_in[5];
    const float* W2     = (const float*)d_in[6];
    const float* a_src2 = (const float*)d_in[7];
    const float* a_dst2 = (const float*)d_in[8];
    const float* b2     = (const float*)d_in[9];
    const float* W3     = (const float*)d_in[10];
    const float* a_src3 = (const float*)d_in[11];
    const float* a_dst3 = (const float*)d_in[12];
    const float* b3     = (const float*)d_in[13];
    const float* Wl     = (const float*)d_in[14];
    const float* bl     = (const float*)d_in[15];
    const float* Wc     = (const float*)d_in[16];
    const float* bc     = (const float*)d_in[17];
    float* out = (float*)d_out;

    const int* src = ei;
    const int* dst = ei + EE;

    // workspace carve
    char* p = (char*)d_ws;
    char* regA = p;  p += (size_t)MPAD*F1*4;            // fp16 ping
    char* regB = p;  p += (size_t)MPAD*F1*4;            // fp16 pong
    _Float16* wt16 = (_Float16*)p;  p += (size_t)F1*F1*2;   // 2.1 MB fp16 weights
    _Float16* x16  = (_Float16*)p;  p += (size_t)NN*IN_DIM*2; // 2.56 MB fp16 x
    float* aw1  = (float*)p;  p += 16*IN_DIM*4;
    float* asrc = (float*)p;  p += (size_t)NN*HEADS*4;
    float* adst = (float*)p;  p += (size_t)NN*HEADS*4;
    int* cnt    = (int*)p;    p += NN*4;
    int* rowp   = (int*)p;    p += (NN+1)*4;
    int* cursor = (int*)p;    p += NN*4;
    int* colsrc = (int*)p;    p += EE*4;

    _Float16* hA = (_Float16*)regA;      // xa -> h2 -> h3 -> lin
    _Float16* hB = (_Float16*)regB;      // out1 -> out2 -> out3

    // ---- CSR build (by dst) ----
    hipMemsetAsync(cnt, 0, NN*sizeof(int), stream);
    count_kernel<<<(EE+255)/256, 256, 0, stream>>>(dst, EE, cnt);
    scan_kernel<<<1, 256, 0, stream>>>(cnt, rowp, cursor, NN);
    fill_kernel<<<(EE+255)/256, 256, 0, stream>>>(src, dst, EE, cursor, colsrc);

    // ---- Layer 1 (agg-first via linearity) ----
    x16_kernel<<<(NN*IN_DIM/4 + 255)/256, 256, 0, stream>>>(x, x16, NN*IN_DIM/4);
    splitT16_kernel<<<dim3(F1/32, IN_DIM/32), 256, 0, stream>>>(W1, wt16, IN_DIM, F1);
    aw1_kernel<<<8, 256, 0, stream>>>(W1, a_src1, a_dst1, aw1);
    alpha1_kernel<<<NN/16, 256, 0, stream>>>(x, aw1, asrc, adst);
    agg1_kernel<<<NN/4, 256, 0, stream>>>(x16, asrc, adst, rowp, colsrc, hA);
    // out1 = relu(xa @ W1 + b1), block-diagonal per head -> hB (fp16)
    mfma16_gemm_kernel<1><<<dim3(MPAD/128, 1, HEADS), 512, 0, stream>>>(
        hA, F1, 128,  wt16, IN_DIM, 128*IN_DIM,
        b1, hB, F1, 128,  IN_DIM, 1);

    // ---- Layer 2 (project-first, fp16) ----
    splitT16_kernel<<<dim3(F1/32, F1/32), 256, 0, stream>>>(W2, wt16, F1, F1);
    mfma16_gemm_kernel<0><<<dim3((F1/128)*(MPAD/128), 1, 1), 512, 0, stream>>>(
        hB, F1, 0,  wt16, F1, 0,
        nullptr, hA, F1, 0,  F1, F1/128);
    alpha16_h8_kernel<<<NN, 128, 0, stream>>>(hA, a_src2, a_dst2, asrc, adst);
    agg2_kernel<<<(NN/4)*8, 256, 0, stream>>>(hA, asrc, adst, rowp, colsrc, b2, hB);

    // ---- Layer 3 (project-first, H=1, fp16) ----
    splitT16_kernel<<<dim3(INT_DIM/32, F1/32), 256, 0, stream>>>(W3, wt16, F1, INT_DIM);
    mfma16_gemm_kernel<0><<<dim3((INT_DIM/128)*(MPAD/128), 1, 1), 512, 0, stream>>>(
        hB, F1, 0,  wt16, F1, 0,
        nullptr, hA, INT_DIM, 0,  F1, INT_DIM/128);
    alpha16_h1_kernel<<<NN, 128, 0, stream>>>(hA, a_src3, a_dst3, asrc, adst);
    agg3_kernel<<<(NN/8)*8, 256, 0, stream>>>(hA, asrc, adst, rowp, colsrc, b3, hB);

    // ---- Linear: relu(out3 @ Wl + bl) -> hA fp16 [NN,512] ----
    splitT16_kernel<<<dim3(INT_DIM/32, INT_DIM/32), 256, 0, stream>>>(Wl, wt16, INT_DIM, INT_DIM);
    mfma16_gemm_kernel<1><<<dim3((INT_DIM/128)*(MPAD/128), 1, 1), 512, 0, stream>>>(
        hB, INT_DIM, 0,  wt16, INT_DIM, 0,
        bl, hA, INT_DIM, 0,  INT_DIM, INT_DIM/128);

    // ---- Classifier ----
    cls16_kernel<<<(NN+3)/4, 256, 0, stream>>>(hA, Wc, bc, out, NN);
}

// Round 15
// 251.628 us; speedup vs baseline: 1.1964x; 1.1964x over previous
//
#include <hip/hip_runtime.h>
#include <hip/hip_bf16.h>

// Problem constants
#define NN 10000
#define EE 160000
#define IN_DIM 128
#define HID 128
#define HEADS 8
#define F1 (HEADS*HID)   // 1024
#define INT_DIM 512
#define OUT_DIM 3
#define MPAD 10112       // 79 * 128

typedef __attribute__((ext_vector_type(4))) float f32x4;
typedef __attribute__((ext_vector_type(8))) _Float16 half8;
typedef __attribute__((ext_vector_type(4))) _Float16 half4;
typedef __attribute__((ext_vector_type(2))) _Float16 half2v;

// wave-local LDS fence: wait all this wave's DS ops, and pin program order
#define WAVE_SYNC() do { asm volatile("s_waitcnt lgkmcnt(0)" ::: "memory"); \
                         __builtin_amdgcn_sched_barrier(0); } while(0)

// ---------------- CSR build ----------------
__global__ __launch_bounds__(256) void count_kernel(const int* __restrict__ dst, int E, int* __restrict__ cnt){
    int e = blockIdx.x*256 + threadIdx.x;
    if(e < E) atomicAdd(&cnt[dst[e]], 1);
}

// single-pass 1024-thread scan: 10 elems/thread serial + shfl wave-scan + cross-wave
__global__ __launch_bounds__(1024) void scan_kernel(const int* __restrict__ cnt, int* __restrict__ rowp,
                                                    int* __restrict__ cursor, int n){
    int t = threadIdx.x;
    int base = t*10;
    int vals[10];
    int run = 0;
    #pragma unroll
    for(int k=0;k<10;k++){
        int i = base+k;
        int v = (i<n) ? cnt[i] : 0;
        vals[k] = run;           // exclusive within thread
        run += v;
    }
    int lane = t & 63, wv = t >> 6;
    int inc = run;               // inclusive wave scan of thread totals
    #pragma unroll
    for(int off=1; off<64; off<<=1){
        int u = __shfl_up(inc, off);
        if(lane >= off) inc += u;
    }
    __shared__ int wtot[16], woff[16];
    if(lane == 63) wtot[wv] = inc;
    __syncthreads();
    if(t < 16){
        int v = wtot[t];
        int inc2 = v;
        #pragma unroll
        for(int off=1; off<16; off<<=1){
            int u = __shfl_up(inc2, off);
            if(t >= off) inc2 += u;
        }
        woff[t] = inc2 - v;      // exclusive wave offset
    }
    __syncthreads();
    int thread_excl = woff[wv] + inc - run;
    #pragma unroll
    for(int k=0;k<10;k++){
        int i = base+k;
        if(i<n){
            int v = thread_excl + vals[k];
            rowp[i] = v;
            cursor[i] = v;
        }
    }
    if(t == 1023) rowp[n] = thread_excl + run;
}

__global__ __launch_bounds__(256) void fill_kernel(const int* __restrict__ src, const int* __restrict__ dst,
                                                   int E, int* __restrict__ cursor, int* __restrict__ colsrc){
    int e = blockIdx.x*256 + threadIdx.x;
    if(e < E){
        int d = dst[e];
        int pos = atomicAdd(&cursor[d], 1);
        colsrc[pos] = src[e];
    }
}

// ---------------- fused prep: 4 weight transposes + x->fp16 + aw1 + cnt zero ----------------
__device__ inline void transpose_tile16(const float* __restrict__ B, _Float16* __restrict__ T,
                                        int K, int N, int idx){
    __shared__ float tile[32][33];
    const int tx = threadIdx.x & 31, ty = threadIdx.x >> 5;   // 32 x 8
    const int gx = N >> 5;
    const int n0 = (idx % gx) * 32, k0 = (idx / gx) * 32;
    #pragma unroll
    for(int i = 0; i < 32; i += 8)
        tile[ty + i][tx] = B[(size_t)(k0 + ty + i) * N + n0 + tx];
    __syncthreads();
    #pragma unroll
    for(int i = 0; i < 32; i += 8){
        int nn = ty + i;
        T[(size_t)(n0 + nn) * K + k0 + tx] = (_Float16)tile[tx][nn];
    }
}

__global__ __launch_bounds__(256) void prep_kernel(
    const float* __restrict__ W1, const float* __restrict__ W2,
    const float* __restrict__ W3, const float* __restrict__ Wl,
    const float* __restrict__ x,
    const float* __restrict__ a_src1, const float* __restrict__ a_dst1,
    _Float16* __restrict__ tW1, _Float16* __restrict__ tW2,
    _Float16* __restrict__ tW3, _Float16* __restrict__ tWl,
    _Float16* __restrict__ x16, float* __restrict__ aw,
    int* __restrict__ cnt)
{
    int b = blockIdx.x;
    if(b < 128){            transpose_tile16(W1, tW1, IN_DIM, F1, b); }
    else if(b < 1152){      transpose_tile16(W2, tW2, F1, F1, b-128); }
    else if(b < 1664){      transpose_tile16(W3, tW3, F1, INT_DIM, b-1152); }
    else if(b < 1920){      transpose_tile16(Wl, tWl, INT_DIM, INT_DIM, b-1664); }
    else if(b < 3170){
        int i = (b-1920)*256 + threadIdx.x;     // < 320000 exactly
        float4 v = ((const float4*)x)[i];
        half4 o = { (_Float16)v.x, (_Float16)v.y, (_Float16)v.z, (_Float16)v.w };
        ((half4*)x16)[i] = o;
    }
    else if(b < 3178){
        int idx = (b-3170)*256 + threadIdx.x;
        if(idx < 16*IN_DIM){
            int j = idx >> 7, k = idx & 127;
            int hj = j & 7;
            const float* av = (j < 8 ? a_src1 : a_dst1) + hj*HID;
            const float* wr = W1 + (size_t)k*F1 + hj*HID;
            float s = 0.f;
            #pragma unroll 4
            for(int c = 0; c < HID; c++) s += av[c] * wr[c];
            aw[idx] = s;
        }
    }
    else {
        int i = (b-3178)*1024 + threadIdx.x*4;
        if(i < NN) *(int4*)(cnt + i) = (int4){0,0,0,0};   // NN%4==0
    }
}

// ---------------- alpha1[n, j] = x[n,:] @ aw[j,:]  -> asrc/adst [NN,8] ----------------
__global__ __launch_bounds__(256) void alpha1_kernel(const float* __restrict__ x,
                                                     const float* __restrict__ aw,
                                                     float* __restrict__ asrc, float* __restrict__ adst){
    __shared__ float xs[16][128];
    __shared__ float aws[16][128];
    int t = threadIdx.x;
    int nb = blockIdx.x * 16;
    for(int i = t; i < 16*128; i += 256){
        xs[i >> 7][i & 127] = x[(size_t)nb*128 + i];
        aws[i >> 7][i & 127] = aw[i];
    }
    __syncthreads();
    int nl = t >> 4, j = t & 15;
    float s = 0.f;
    #pragma unroll 4
    for(int c = 0; c < 128; c++) s += xs[nl][c] * aws[j][c];
    int node = nb + nl;
    if(j < 8) asrc[node*8 + j] = s;
    else      adst[node*8 + (j-8)] = s;
}

// ---------------- agg1: per-head softmax-agg of fp16 x; 4 nodes/block, 1 wave/node; emits fp16 ----------------
__global__ __launch_bounds__(256) void agg1_kernel(const _Float16* __restrict__ x16,
                                                   const float* __restrict__ asrc,
                                                   const float* __restrict__ adst,
                                                   const int* __restrict__ rowp,
                                                   const int* __restrict__ colsrc,
                                                   _Float16* __restrict__ oa){
    const int w = threadIdx.x >> 6, l = threadIdx.x & 63;
    const int node = blockIdx.x*4 + w;
    __shared__ float sh_ee[4][64][8];
    int beg = rowp[node], end = rowp[node+1];
    float rd = adst[node*8 + (l & 7)];
    float acc0[8], acc1[8];
    #pragma unroll
    for(int h=0;h<8;h++){ acc0[h]=0.f; acc1[h]=0.f; }
    float dpart = 0.f;
    for(int base=beg; base<end; base+=64){
        int clen = min(64, end-base);
        WAVE_SYNC();                        // prior chunk's ee reads complete
        int sreg = (l < clen) ? colsrc[base + l] : 0;
        for(int it=l; it<clen*8; it+=64){
            int j = it >> 3;
            int s = colsrc[base + j];
            float e = asrc[s*8 + (l & 7)] + rd;
            e = (e > 0.f) ? e : 0.2f*e;
            float ee = expf(e);
            sh_ee[w][j][l & 7] = ee;
            dpart += ee;
        }
        WAVE_SYNC();                        // ee visible wave-wide
        #pragma unroll 2
        for(int j=0;j<clen;j++){
            int s = __shfl(sreg, j);
            half2v xv = ((const half2v*)(x16 + (size_t)s*128))[l];
            float x0 = (float)xv[0], x1 = (float)xv[1];
            #pragma unroll
            for(int h=0;h<8;h++){
                float wt = sh_ee[w][j][h];
                acc0[h] += wt * x0;
                acc1[h] += wt * x1;
            }
        }
    }
    dpart += __shfl_xor(dpart, 8);
    dpart += __shfl_xor(dpart, 16);
    dpart += __shfl_xor(dpart, 32);         // lane l holds denom for head l&7
    #pragma unroll
    for(int h=0;h<8;h++){
        float dn = __shfl(dpart, h) + 1e-16f;
        half2v o = { (_Float16)(acc0[h]/dn), (_Float16)(acc1[h]/dn) };
        *(half2v*)(oa + (size_t)node*F1 + h*128 + 2*l) = o;
    }
}

// ---------------- agg2: head-partitioned gather; 16-lane group per edge, half8 per lane ----------------
__global__ __launch_bounds__(256) void agg2_kernel(const _Float16* __restrict__ hbuf,
                                                   const float* __restrict__ asrc,
                                                   const float* __restrict__ adst,
                                                   const int* __restrict__ rowp,
                                                   const int* __restrict__ colsrc,
                                                   const float* __restrict__ bias,
                                                   _Float16* __restrict__ oa){
    const int w = threadIdx.x >> 6, l = threadIdx.x & 63;
    const int h = blockIdx.x & 7;
    const int node = (blockIdx.x >> 3)*4 + w;
    const int g = l >> 4, i = l & 15;    // group g -> edge j0+g; lane i -> features 8i..8i+7
    int beg = rowp[node], end = rowp[node+1];
    float rd = adst[node*8 + h];
    float acc[8];
    #pragma unroll
    for(int k=0;k<8;k++) acc[k]=0.f;
    float dpart = 0.f;
    const _Float16* hb = hbuf + h*128 + 8*i;
    for(int base=beg; base<end; base+=64){
        int clen = min(64, end-base);
        int sreg = 0; float eereg = 0.f;
        if(l < clen){
            sreg = colsrc[base + l];
            float e = asrc[sreg*8 + h] + rd;
            e = (e > 0.f) ? e : 0.2f*e;
            eereg = expf(e);
            dpart += eereg;
        }
        int cpad = (clen + 3) & ~3;
        int s0 = __shfl(sreg, g);
        float w0 = __shfl(eereg, g);
        half8 v0 = *(const half8*)(hb + (size_t)s0*F1);
        #pragma unroll 1
        for(int j0=0; j0<cpad; j0+=4){
            half8 nv; float nw = 0.f;
            const bool more = (j0+4 < cpad);
            if(more){
                int ns = __shfl(sreg, j0+4+g);
                nw = __shfl(eereg, j0+4+g);
                nv = *(const half8*)(hb + (size_t)ns*F1);
            }
            #pragma unroll
            for(int k=0;k<8;k++) acc[k] += w0 * (float)v0[k];
            if(more){ v0 = nv; w0 = nw; }
        }
    }
    #pragma unroll
    for(int k=0;k<8;k++){
        acc[k] += __shfl_xor(acc[k], 16);
        acc[k] += __shfl_xor(acc[k], 32);
    }
    #pragma unroll
    for(int off=1; off<64; off<<=1) dpart += __shfl_xor(dpart, off);
    float dn = dpart + 1e-16f;
    if(g == 0){
        const int f = h*128 + 8*i;
        float4 b0 = *(const float4*)(bias + f);
        float4 b1 = *(const float4*)(bias + f + 4);
        float bb[8] = {b0.x,b0.y,b0.z,b0.w, b1.x,b1.y,b1.z,b1.w};
        half8 o;
        #pragma unroll
        for(int k=0;k<8;k++)
            o[k] = (_Float16)fmaxf(acc[k]/dn + bb[k], 0.f);
        *(half8*)(oa + (size_t)node*F1 + f) = o;
    }
}

// ---------------- agg3: chunk-partitioned gather (H=1); 16-lane group per edge, half8 per lane ----------------
__global__ __launch_bounds__(256) void agg3_kernel(const _Float16* __restrict__ hbuf,
                                                   const float* __restrict__ asrc,
                                                   const float* __restrict__ adst,
                                                   const int* __restrict__ rowp,
                                                   const int* __restrict__ colsrc,
                                                   const float* __restrict__ bias,
                                                   _Float16* __restrict__ oa){
    const int w = threadIdx.x >> 6, l = threadIdx.x & 63;
    const int i7 = blockIdx.x & 7;
    const int chunk = i7 & 3, sub = i7 >> 2;
    const int node = ((blockIdx.x >> 3)*2 + sub)*4 + w;
    const int g = l >> 4, i = l & 15;
    int beg = rowp[node], end = rowp[node+1];
    float rd = adst[node];
    float acc[8];
    #pragma unroll
    for(int k=0;k<8;k++) acc[k]=0.f;
    float dpart = 0.f;
    const _Float16* hb = hbuf + chunk*128 + 8*i;
    for(int base=beg; base<end; base+=64){
        int clen = min(64, end-base);
        int sreg = 0; float eereg = 0.f;
        if(l < clen){
            sreg = colsrc[base + l];
            float e = asrc[sreg] + rd;
            e = (e > 0.f) ? e : 0.2f*e;
            eereg = expf(e);
            dpart += eereg;
        }
        int cpad = (clen + 3) & ~3;
        int s0 = __shfl(sreg, g);
        float w0 = __shfl(eereg, g);
        half8 v0 = *(const half8*)(hb + (size_t)s0*INT_DIM);
        #pragma unroll 1
        for(int j0=0; j0<cpad; j0+=4){
            half8 nv; float nw = 0.f;
            const bool more = (j0+4 < cpad);
            if(more){
                int ns = __shfl(sreg, j0+4+g);
                nw = __shfl(eereg, j0+4+g);
                nv = *(const half8*)(hb + (size_t)ns*INT_DIM);
            }
            #pragma unroll
            for(int k=0;k<8;k++) acc[k] += w0 * (float)v0[k];
            if(more){ v0 = nv; w0 = nw; }
        }
    }
    #pragma unroll
    for(int k=0;k<8;k++){
        acc[k] += __shfl_xor(acc[k], 16);
        acc[k] += __shfl_xor(acc[k], 32);
    }
    #pragma unroll
    for(int off=1; off<64; off<<=1) dpart += __shfl_xor(dpart, off);
    float dn = dpart + 1e-16f;
    if(g == 0){
        const int f = chunk*128 + 8*i;
        float4 b0 = *(const float4*)(bias + f);
        float4 b1 = *(const float4*)(bias + f + 4);
        float bb[8] = {b0.x,b0.y,b0.z,b0.w, b1.x,b1.y,b1.z,b1.w};
        half8 o;
        #pragma unroll
        for(int k=0;k<8;k++)
            o[k] = (_Float16)fmaxf(acc[k]/dn + bb[k], 0.f);
        *(half8*)(oa + (size_t)node*INT_DIM + f) = o;
    }
}

// ---------------- single-pass fp16 MFMA GEMM, 8 waves (2x4), 128x128 tile, dbuf 2-phase ----------------
template<int FUSE>
__global__ __launch_bounds__(512, 4) void mfma16_gemm_kernel(
    const _Float16* __restrict__ A, int lda, int za,
    const _Float16* __restrict__ B, int ldb, int zb,
    const float* __restrict__ bias, _Float16* __restrict__ O,
    int ldc, int zc, int K, int gx)
{
    __shared__ _Float16 lA[2][128*32];   // 8 KB per buffer
    __shared__ _Float16 lB[2][128*32];
    const int tid  = threadIdx.x;
    const int lane = tid & 63;
    const int w    = tid >> 6;      // 0..7
    const int wm   = w >> 2;        // 0..1 (row half)
    const int wn   = w & 3;         // 0..3 (col quarter)
    const int z    = blockIdx.z;

    // XCD-bijective swizzle
    const int nwg = gridDim.x;
    const int q = nwg >> 3, r = nwg & 7;
    const int xcd = blockIdx.x & 7, idx = blockIdx.x >> 3;
    const int wgid = (xcd < r ? xcd*(q+1) : r*(q+1) + (xcd-r)*q) + idx;
    const int row0 = (wgid / gx) * 128, col0 = (wgid % gx) * 128;

    f32x4 acc[4][2];
    #pragma unroll
    for(int i=0;i<4;i++)
        #pragma unroll
        for(int j=0;j<2;j++) acc[i][j] = (f32x4){0.f,0.f,0.f,0.f};

    // staging: 512 lanes cover 128 rows x 4 slots of 16B; LDS slot written = tid&3
    const int rr1 = tid >> 2;                        // 0..127
    const int ss1 = (tid & 3) ^ ((rr1 >> 1) & 3);    // swizzled global slot
    const size_t aoff = (size_t)(row0 + rr1) * lda + (size_t)z*za + ss1 * 8;
    const size_t boff = (size_t)(col0 + rr1) * ldb + (size_t)z*zb + ss1 * 8;

    typedef __attribute__((address_space(3))) char lds_char;
    lds_char* dA = (lds_char*)(&lA[0][0]) + w*1024;
    lds_char* dB = (lds_char*)(&lB[0][0]) + w*1024;

    int arow[4], brow[2];
    const int slotx = ((lane >> 4) ^ ((lane >> 1) & 3)) << 4;
    #pragma unroll
    for(int i=0;i<4;i++)
        arow[i] = (wm*64 + i*16 + (lane & 15)) * 64 + slotx;
    #pragma unroll
    for(int j=0;j<2;j++)
        brow[j] = (wn*32 + j*16 + (lane & 15)) * 64 + slotx;

    #define GLDS(src, dst) __builtin_amdgcn_global_load_lds( \
        (__attribute__((address_space(1))) void*)(src), \
        (__attribute__((address_space(3))) void*)(dst), 16, 0, 0)
    GLDS(A + aoff, dA);
    GLDS(B + boff, dB);
    __syncthreads();

    #pragma unroll 1
    for(int k0 = 0, kb = 0; k0 < K; k0 += 32, kb ^= 1){
        if(k0 + 32 < K){
            const int nb = kb ^ 1;
            GLDS(A + aoff + k0 + 32, dA + nb*8192);
            GLDS(B + boff + k0 + 32, dB + nb*8192);
        }
        const char* pA = (const char*)(&lA[0][0]) + kb*8192;
        const char* pB = (const char*)(&lB[0][0]) + kb*8192;
        half8 af[4];
        #pragma unroll
        for(int i=0;i<4;i++) af[i] = *(const half8*)(pA + arow[i]);
        #pragma unroll
        for(int j=0;j<2;j++){
            half8 bf = *(const half8*)(pB + brow[j]);
            #pragma unroll
            for(int i=0;i<4;i++)
                acc[i][j] = __builtin_amdgcn_mfma_f32_16x16x32_f16(af[i], bf, acc[i][j], 0, 0, 0);
        }
        __syncthreads();
    }
    #undef GLDS

    // epilogue: C/D layout col=lane&15, row=(lane>>4)*4+reg
    #pragma unroll
    for(int i=0;i<4;i++){
        const int rr = row0 + wm*64 + i*16 + ((lane >> 4) << 2);
        #pragma unroll
        for(int j=0;j<2;j++){
            const int gc = z*zc + col0 + wn*32 + j*16 + (lane & 15);
            float b = FUSE ? bias[gc] : 0.f;
            #pragma unroll
            for(int rg=0;rg<4;rg++){
                float v = acc[i][j][rg];
                if(FUSE) v = fmaxf(v + b, 0.f);
                O[(size_t)(rr + rg) * ldc + gc] = (_Float16)v;
            }
        }
    }
}

// ---------------- alpha from fp16 h: H=8, C=128 ----------------
__global__ __launch_bounds__(128) void alpha16_h8_kernel(const _Float16* __restrict__ hbuf,
                                                         const float* __restrict__ a_src,
                                                         const float* __restrict__ a_dst,
                                                         float* __restrict__ asrc, float* __restrict__ adst){
    int node = blockIdx.x;
    int t = threadIdx.x;          // 128 threads; features 8t..8t+7, head t>>4
    half8 v = ((const half8*)(hbuf + (size_t)node*F1))[t];
    const float4* ap = (const float4*)(a_src + 8*t);
    const float4* dp = (const float4*)(a_dst + 8*t);
    float4 a0 = ap[0], a1 = ap[1];
    float4 d0 = dp[0], d1 = dp[1];
    float av[8] = {a0.x,a0.y,a0.z,a0.w, a1.x,a1.y,a1.z,a1.w};
    float dv[8] = {d0.x,d0.y,d0.z,d0.w, d1.x,d1.y,d1.z,d1.w};
    float ps = 0.f, pd = 0.f;
    #pragma unroll
    for(int k=0;k<8;k++){
        float f = (float)v[k];
        ps += f * av[k];
        pd += f * dv[k];
    }
    #pragma unroll
    for(int off=8; off; off>>=1){ ps += __shfl_down(ps, off); pd += __shfl_down(pd, off); }
    if((t & 15) == 0){
        asrc[(size_t)node*8 + (t>>4)] = ps;
        adst[(size_t)node*8 + (t>>4)] = pd;
    }
}

// ---------------- alpha from fp16 h: H=1, C=512 ----------------
__global__ __launch_bounds__(128) void alpha16_h1_kernel(const _Float16* __restrict__ hbuf,
                                                         const float* __restrict__ a_src,
                                                         const float* __restrict__ a_dst,
                                                         float* __restrict__ asrc, float* __restrict__ adst){
    int node = blockIdx.x;
    int t = threadIdx.x;          // 128 threads; features 4t..4t+3
    half4 v = ((const half4*)(hbuf + (size_t)node*INT_DIM))[t];
    float4 a = ((const float4*)a_src)[t];
    float4 d = ((const float4*)a_dst)[t];
    float ps = (float)v[0]*a.x + (float)v[1]*a.y + (float)v[2]*a.z + (float)v[3]*a.w;
    float pd = (float)v[0]*d.x + (float)v[1]*d.y + (float)v[2]*d.z + (float)v[3]*d.w;
    #pragma unroll
    for(int off=32; off; off>>=1){ ps += __shfl_down(ps, off); pd += __shfl_down(pd, off); }
    __shared__ float shs[2], shd[2];
    int wv = t >> 6;
    if((t & 63) == 0){ shs[wv] = ps; shd[wv] = pd; }
    __syncthreads();
    if(t == 0){
        asrc[node] = shs[0] + shs[1];
        adst[node] = shd[0] + shd[1];
    }
}

// ---------------- classifier: out[n,3] = h16[n,:512] @ Wc + bc ----------------
__global__ __launch_bounds__(256) void cls16_kernel(const _Float16* __restrict__ h, const float* __restrict__ Wc,
                                                    const float* __restrict__ bc, float* __restrict__ out, int n){
    int node = blockIdx.x*4 + (threadIdx.x >> 6);
    int lane = threadIdx.x & 63;
    if(node >= n) return;
    half8 v = ((const half8*)(h + (size_t)node*INT_DIM))[lane];  // features 8l..8l+7
    float s0=0.f, s1=0.f, s2=0.f;
    #pragma unroll
    for(int k=0;k<8;k++){
        float f = (float)v[k];
        const float* wr = Wc + (8*lane + k)*3;
        s0 += f * wr[0];
        s1 += f * wr[1];
        s2 += f * wr[2];
    }
    #pragma unroll
    for(int off=32; off; off>>=1){
        s0 += __shfl_down(s0, off);
        s1 += __shfl_down(s1, off);
        s2 += __shfl_down(s2, off);
    }
    if(lane==0){
        out[(size_t)node*3+0] = s0 + bc[0];
        out[(size_t)node*3+1] = s1 + bc[1];
        out[(size_t)node*3+2] = s2 + bc[2];
    }
}

extern "C" void kernel_launch(void* const* d_in, const int* in_sizes, int n_in,
                              void* d_out, int out_size, void* d_ws, size_t ws_size,
                              hipStream_t stream){
    const float* x      = (const float*)d_in[0];
    const int*   ei     = (const int*)d_in[1];
    const float* W1     = (const float*)d_in[2];
    const float* a_src1 = (const float*)d_in[3];
    const float* a_dst1 = (const float*)d_in[4];
    const float* b1     = (const float*)d_in[5];
    const float* W2     = (const float*)d_in[6];
    const float* a_src2 = (const float*)d_in[7];
    const float* a_dst2 = (const float*)d_in[8];
    const float* b2     = (const float*)d_in[9];
    const float* W3     = (const float*)d_in[10];
    const float* a_src3 = (const float*)d_in[11];
    const float* a_dst3 = (const float*)d_in[12];
    const float* b3     = (const float*)d_in[13];
    const float* Wl     = (const float*)d_in[14];
    const float* bl     = (const float*)d_in[15];
    const float* Wc     = (const float*)d_in[16];
    const float* bc     = (const float*)d_in[17];
    float* out = (float*)d_out;

    const int* src = ei;
    const int* dst = ei + EE;

    // workspace carve: two 41.4MB regions; hA/hB (fp16, 20.7MB each) use the lower halves,
    // weights + x16 live in regA's free upper half.
    char* p = (char*)d_ws;
    char* regA = p;  p += (size_t)MPAD*F1*4;
    char* regB = p;  p += (size_t)MPAD*F1*4;
    float* aw1  = (float*)p;  p += 16*IN_DIM*4;
    float* asrc = (float*)p;  p += (size_t)NN*HEADS*4;
    float* adst = (float*)p;  p += (size_t)NN*HEADS*4;
    int* cnt    = (int*)p;    p += NN*4;
    int* rowp   = (int*)p;    p += (NN+1)*4;
    int* cursor = (int*)p;    p += NN*4;
    int* colsrc = (int*)p;    p += EE*4;

    _Float16* hA = (_Float16*)regA;      // xa -> h2 -> h3 -> lin
    _Float16* hB = (_Float16*)regB;      // out1 -> out2 -> out3
    _Float16* up   = (_Float16*)(regA + (size_t)MPAD*F1*2);   // free upper half of regA
    _Float16* tW1  = up;                        // 1024*128
    _Float16* tW2  = tW1 + (size_t)F1*IN_DIM;   // 1024*1024
    _Float16* tW3  = tW2 + (size_t)F1*F1;       // 512*1024
    _Float16* tWl  = tW3 + (size_t)INT_DIM*F1;  // 512*512
    _Float16* x16  = tWl + (size_t)INT_DIM*INT_DIM;  // 10000*128

    // ---- fused prep (weights/x16/aw1/cnt-zero) + CSR build ----
    prep_kernel<<<3188, 256, 0, stream>>>(W1, W2, W3, Wl, x, a_src1, a_dst1,
                                          tW1, tW2, tW3, tWl, x16, aw1, cnt);
    count_kernel<<<(EE+255)/256, 256, 0, stream>>>(dst, EE, cnt);
    scan_kernel<<<1, 1024, 0, stream>>>(cnt, rowp, cursor, NN);
    fill_kernel<<<(EE+255)/256, 256, 0, stream>>>(src, dst, EE, cursor, colsrc);

    // ---- Layer 1 (agg-first via linearity) ----
    alpha1_kernel<<<NN/16, 256, 0, stream>>>(x, aw1, asrc, adst);
    agg1_kernel<<<NN/4, 256, 0, stream>>>(x16, asrc, adst, rowp, colsrc, hA);
    mfma16_gemm_kernel<1><<<dim3(MPAD/128, 1, HEADS), 512, 0, stream>>>(
        hA, F1, 128,  tW1, IN_DIM, 128*IN_DIM,
        b1, hB, F1, 128,  IN_DIM, 1);

    // ---- Layer 2 (project-first, fp16) ----
    mfma16_gemm_kernel<0><<<dim3((F1/128)*(MPAD/128), 1, 1), 512, 0, stream>>>(
        hB, F1, 0,  tW2, F1, 0,
        nullptr, hA, F1, 0,  F1, F1/128);
    alpha16_h8_kernel<<<NN, 128, 0, stream>>>(hA, a_src2, a_dst2, asrc, adst);
    agg2_kernel<<<(NN/4)*8, 256, 0, stream>>>(hA, asrc, adst, rowp, colsrc, b2, hB);

    // ---- Layer 3 (project-first, H=1, fp16) ----
    mfma16_gemm_kernel<0><<<dim3((INT_DIM/128)*(MPAD/128), 1, 1), 512, 0, stream>>>(
        hB, F1, 0,  tW3, F1, 0,
        nullptr, hA, INT_DIM, 0,  F1, INT_DIM/128);
    alpha16_h1_kernel<<<NN, 128, 0, stream>>>(hA, a_src3, a_dst3, asrc, adst);
    agg3_kernel<<<(NN/8)*8, 256, 0, stream>>>(hA, asrc, adst, rowp, colsrc, b3, hB);

    // ---- Linear: relu(out3 @ Wl + bl) -> hA fp16 [NN,512] ----
    mfma16_gemm_kernel<1><<<dim3((INT_DIM/128)*(MPAD/128), 1, 1), 512, 0, stream>>>(
        hB, INT_DIM, 0,  tWl, INT_DIM, 0,
        bl, hA, INT_DIM, 0,  INT_DIM, INT_DIM/128);

    // ---- Classifier ----
    cls16_kernel<<<(NN+3)/4, 256, 0, stream>>>(hA, Wc, bc, out, NN);
}

// Round 16
// 245.326 us; speedup vs baseline: 1.2272x; 1.0257x over previous
//
#include <hip/hip_runtime.h>
#include <hip/hip_bf16.h>

// Problem constants
#define NN 10000
#define EE 160000
#define IN_DIM 128
#define HID 128
#define HEADS 8
#define F1 (HEADS*HID)   // 1024
#define INT_DIM 512
#define OUT_DIM 3
#define MPAD 10112       // 79 * 128

typedef __attribute__((ext_vector_type(4))) float f32x4;
typedef __attribute__((ext_vector_type(8))) _Float16 half8;
typedef __attribute__((ext_vector_type(4))) _Float16 half4;
typedef __attribute__((ext_vector_type(2))) _Float16 half2v;

// wave-local LDS fence: wait all this wave's DS ops, and pin program order
#define WAVE_SYNC() do { asm volatile("s_waitcnt lgkmcnt(0)" ::: "memory"); \
                         __builtin_amdgcn_sched_barrier(0); } while(0)

// fp32 acc += f32(w) * f16-half-of(pair)  — v_fma_mix_f32, no separate cvt
#define FMA_MIX_LO(acc, pair, w) asm("v_fma_mix_f32 %0, %1, %2, %0 op_sel:[0,0,0] op_sel_hi:[1,0,0]" \
                                     : "+v"(acc) : "v"(pair), "v"(w))
#define FMA_MIX_HI(acc, pair, w) asm("v_fma_mix_f32 %0, %1, %2, %0 op_sel:[1,0,0] op_sel_hi:[1,0,0]" \
                                     : "+v"(acc) : "v"(pair), "v"(w))

// ---------------- CSR build ----------------
// single-pass 1024-thread scan: 10 elems/thread serial + shfl wave-scan + cross-wave
__global__ __launch_bounds__(1024) void scan_kernel(const int* __restrict__ cnt, int* __restrict__ rowp,
                                                    int* __restrict__ cursor, int n){
    int t = threadIdx.x;
    int base = t*10;
    int vals[10];
    int run = 0;
    #pragma unroll
    for(int k=0;k<10;k++){
        int i = base+k;
        int v = (i<n) ? cnt[i] : 0;
        vals[k] = run;           // exclusive within thread
        run += v;
    }
    int lane = t & 63, wv = t >> 6;
    int inc = run;               // inclusive wave scan of thread totals
    #pragma unroll
    for(int off=1; off<64; off<<=1){
        int u = __shfl_up(inc, off);
        if(lane >= off) inc += u;
    }
    __shared__ int wtot[16], woff[16];
    if(lane == 63) wtot[wv] = inc;
    __syncthreads();
    if(t < 16){
        int v = wtot[t];
        int inc2 = v;
        #pragma unroll
        for(int off=1; off<16; off<<=1){
            int u = __shfl_up(inc2, off);
            if(t >= off) inc2 += u;
        }
        woff[t] = inc2 - v;      // exclusive wave offset
    }
    __syncthreads();
    int thread_excl = woff[wv] + inc - run;
    #pragma unroll
    for(int k=0;k<10;k++){
        int i = base+k;
        if(i<n){
            int v = thread_excl + vals[k];
            rowp[i] = v;
            cursor[i] = v;
        }
    }
    if(t == 1023) rowp[n] = thread_excl + run;
}

__global__ __launch_bounds__(256) void fill_kernel(const int* __restrict__ src, const int* __restrict__ dst,
                                                   int E, int* __restrict__ cursor, int* __restrict__ colsrc){
    int e = blockIdx.x*256 + threadIdx.x;
    if(e < E){
        int d = dst[e];
        int pos = atomicAdd(&cursor[d], 1);
        colsrc[pos] = src[e];
    }
}

// ---------------- fused prep: 4 weight transposes + x->fp16 + aw1 + cnt zero ----------------
__device__ inline void transpose_tile16(const float* __restrict__ B, _Float16* __restrict__ T,
                                        int K, int N, int idx){
    __shared__ float tile[32][33];
    const int tx = threadIdx.x & 31, ty = threadIdx.x >> 5;   // 32 x 8
    const int gx = N >> 5;
    const int n0 = (idx % gx) * 32, k0 = (idx / gx) * 32;
    #pragma unroll
    for(int i = 0; i < 32; i += 8)
        tile[ty + i][tx] = B[(size_t)(k0 + ty + i) * N + n0 + tx];
    __syncthreads();
    #pragma unroll
    for(int i = 0; i < 32; i += 8){
        int nn = ty + i;
        T[(size_t)(n0 + nn) * K + k0 + tx] = (_Float16)tile[tx][nn];
    }
}

__global__ __launch_bounds__(256) void prep_kernel(
    const float* __restrict__ W1, const float* __restrict__ W2,
    const float* __restrict__ W3, const float* __restrict__ Wl,
    const float* __restrict__ x,
    const float* __restrict__ a_src1, const float* __restrict__ a_dst1,
    _Float16* __restrict__ tW1, _Float16* __restrict__ tW2,
    _Float16* __restrict__ tW3, _Float16* __restrict__ tWl,
    _Float16* __restrict__ x16, float* __restrict__ aw,
    int* __restrict__ cnt)
{
    int b = blockIdx.x;
    if(b < 128){            transpose_tile16(W1, tW1, IN_DIM, F1, b); }
    else if(b < 1152){      transpose_tile16(W2, tW2, F1, F1, b-128); }
    else if(b < 1664){      transpose_tile16(W3, tW3, F1, INT_DIM, b-1152); }
    else if(b < 1920){      transpose_tile16(Wl, tWl, INT_DIM, INT_DIM, b-1664); }
    else if(b < 3170){
        int i = (b-1920)*256 + threadIdx.x;     // < 320000 exactly
        float4 v = ((const float4*)x)[i];
        half4 o = { (_Float16)v.x, (_Float16)v.y, (_Float16)v.z, (_Float16)v.w };
        ((half4*)x16)[i] = o;
    }
    else if(b < 3178){
        int idx = (b-3170)*256 + threadIdx.x;
        if(idx < 16*IN_DIM){
            int j = idx >> 7, k = idx & 127;
            int hj = j & 7;
            const float* av = (j < 8 ? a_src1 : a_dst1) + hj*HID;
            const float* wr = W1 + (size_t)k*F1 + hj*HID;
            float s = 0.f;
            #pragma unroll 4
            for(int c = 0; c < HID; c++) s += av[c] * wr[c];
            aw[idx] = s;
        }
    }
    else {
        int i = (b-3178)*1024 + threadIdx.x*4;
        if(i < NN) *(int4*)(cnt + i) = (int4){0,0,0,0};   // NN%4==0
    }
}

// ---------------- fused: count (blocks 0..624) + alpha1 (blocks 625..1249) ----------------
__global__ __launch_bounds__(256) void count_alpha1_kernel(
    const int* __restrict__ dst, int* __restrict__ cnt,
    const float* __restrict__ x, const float* __restrict__ aw,
    float* __restrict__ asrc, float* __restrict__ adst)
{
    int b = blockIdx.x;
    if(b < 625){
        int e = b*256 + threadIdx.x;
        if(e < EE) atomicAdd(&cnt[dst[e]], 1);
        return;
    }
    __shared__ float xs[16][128];
    __shared__ float aws[16][128];
    int t = threadIdx.x;
    int nb = (b - 625) * 16;
    for(int i = t; i < 16*128; i += 256){
        xs[i >> 7][i & 127] = x[(size_t)nb*128 + i];
        aws[i >> 7][i & 127] = aw[i];
    }
    __syncthreads();
    int nl = t >> 4, j = t & 15;
    float s = 0.f;
    #pragma unroll 4
    for(int c = 0; c < 128; c++) s += xs[nl][c] * aws[j][c];
    int node = nb + nl;
    if(j < 8) asrc[node*8 + j] = s;
    else      adst[node*8 + (j-8)] = s;
}

// ---------------- agg1: per-head softmax-agg of fp16 x; 4 nodes/block, 1 wave/node; emits fp16 ----------------
__global__ __launch_bounds__(256) void agg1_kernel(const _Float16* __restrict__ x16,
                                                   const float* __restrict__ asrc,
                                                   const float* __restrict__ adst,
                                                   const int* __restrict__ rowp,
                                                   const int* __restrict__ colsrc,
                                                   _Float16* __restrict__ oa){
    const int w = threadIdx.x >> 6, l = threadIdx.x & 63;
    const int node = blockIdx.x*4 + w;
    __shared__ float sh_ee[4][64][8];
    int beg = rowp[node], end = rowp[node+1];
    float rd = adst[node*8 + (l & 7)];
    float acc0[8], acc1[8];
    #pragma unroll
    for(int h=0;h<8;h++){ acc0[h]=0.f; acc1[h]=0.f; }
    float dpart = 0.f;
    const char* xb = (const char*)x16 + 4*l;
    for(int base=beg; base<end; base+=64){
        int clen = min(64, end-base);
        WAVE_SYNC();                        // prior chunk's ee reads complete
        unsigned soff = 0;
        if(l < clen) soff = (unsigned)colsrc[base + l] << 8;   // row byte offset (256B rows)
        for(int it=l; it<clen*8; it+=64){
            int j = it >> 3;
            int s = colsrc[base + j];
            float e = asrc[s*8 + (l & 7)] + rd;
            e = (e > 0.f) ? e : 0.2f*e;
            float ee = expf(e);
            sh_ee[w][j][l & 7] = ee;
            dpart += ee;
        }
        WAVE_SYNC();                        // ee visible wave-wide
        #pragma unroll 2
        for(int j=0;j<clen;j++){
            unsigned o = (unsigned)__shfl((int)soff, j);
            unsigned pair = *(const unsigned*)(xb + o);
            #pragma unroll
            for(int h=0;h<8;h++){
                float wt = sh_ee[w][j][h];
                FMA_MIX_LO(acc0[h], pair, wt);
                FMA_MIX_HI(acc1[h], pair, wt);
            }
        }
    }
    dpart += __shfl_xor(dpart, 8);
    dpart += __shfl_xor(dpart, 16);
    dpart += __shfl_xor(dpart, 32);         // lane l holds denom for head l&7
    #pragma unroll
    for(int h=0;h<8;h++){
        float dn = __shfl(dpart, h) + 1e-16f;
        half2v o = { (_Float16)(acc0[h]/dn), (_Float16)(acc1[h]/dn) };
        *(half2v*)(oa + (size_t)node*F1 + h*128 + 2*l) = o;
    }
}

// ---------------- agg2: head-partitioned gather; 16-lane group per edge; fma_mix + 32-bit addr ----------------
__global__ __launch_bounds__(256) void agg2_kernel(const _Float16* __restrict__ hbuf,
                                                   const float* __restrict__ asrc,
                                                   const float* __restrict__ adst,
                                                   const int* __restrict__ rowp,
                                                   const int* __restrict__ colsrc,
                                                   const float* __restrict__ bias,
                                                   _Float16* __restrict__ oa){
    const int w = threadIdx.x >> 6, l = threadIdx.x & 63;
    const int h = blockIdx.x & 7;
    const int node = (blockIdx.x >> 3)*4 + w;
    const int g = l >> 4, i = l & 15;    // group g -> edge j0+g; lane i -> features 8i..8i+7
    int beg = rowp[node], end = rowp[node+1];
    float rd = adst[node*8 + h];
    float acc[8];
    #pragma unroll
    for(int k=0;k<8;k++) acc[k]=0.f;
    float dpart = 0.f;
    const char* hb = (const char*)hbuf + h*256 + 16*i;
    for(int base=beg; base<end; base+=64){
        int clen = min(64, end-base);
        unsigned soff = 0; float eereg = 0.f;
        if(l < clen){
            int s = colsrc[base + l];
            soff = (unsigned)s << 11;        // row byte offset (2048B rows)
            float e = asrc[s*8 + h] + rd;
            e = (e > 0.f) ? e : 0.2f*e;
            eereg = expf(e);
            dpart += eereg;
        }
        int cpad = (clen + 3) & ~3;
        unsigned o0 = (unsigned)__shfl((int)soff, g);
        float w0 = __shfl(eereg, g);
        uint4 v0 = *(const uint4*)(hb + o0);
        #pragma unroll 1
        for(int j0=0; j0<cpad; j0+=4){
            uint4 nv; float nw = 0.f;
            const bool more = (j0+4 < cpad);
            if(more){
                unsigned no = (unsigned)__shfl((int)soff, j0+4+g);
                nw = __shfl(eereg, j0+4+g);
                nv = *(const uint4*)(hb + no);
            }
            FMA_MIX_LO(acc[0], v0.x, w0);  FMA_MIX_HI(acc[1], v0.x, w0);
            FMA_MIX_LO(acc[2], v0.y, w0);  FMA_MIX_HI(acc[3], v0.y, w0);
            FMA_MIX_LO(acc[4], v0.z, w0);  FMA_MIX_HI(acc[5], v0.z, w0);
            FMA_MIX_LO(acc[6], v0.w, w0);  FMA_MIX_HI(acc[7], v0.w, w0);
            if(more){ v0 = nv; w0 = nw; }
        }
    }
    #pragma unroll
    for(int k=0;k<8;k++){
        acc[k] += __shfl_xor(acc[k], 16);
        acc[k] += __shfl_xor(acc[k], 32);
    }
    #pragma unroll
    for(int off=1; off<64; off<<=1) dpart += __shfl_xor(dpart, off);
    float dn = dpart + 1e-16f;
    if(g == 0){
        const int f = h*128 + 8*i;
        float4 b0 = *(const float4*)(bias + f);
        float4 b1 = *(const float4*)(bias + f + 4);
        float bb[8] = {b0.x,b0.y,b0.z,b0.w, b1.x,b1.y,b1.z,b1.w};
        half8 o;
        #pragma unroll
        for(int k=0;k<8;k++)
            o[k] = (_Float16)fmaxf(acc[k]/dn + bb[k], 0.f);
        *(half8*)(oa + (size_t)node*F1 + f) = o;
    }
}

// ---------------- agg3: chunk-partitioned gather (H=1); 16-lane group per edge; fma_mix ----------------
__global__ __launch_bounds__(256) void agg3_kernel(const _Float16* __restrict__ hbuf,
                                                   const float* __restrict__ asrc,
                                                   const float* __restrict__ adst,
                                                   const int* __restrict__ rowp,
                                                   const int* __restrict__ colsrc,
                                                   const float* __restrict__ bias,
                                                   _Float16* __restrict__ oa){
    const int w = threadIdx.x >> 6, l = threadIdx.x & 63;
    const int i7 = blockIdx.x & 7;
    const int chunk = i7 & 3, sub = i7 >> 2;
    const int node = ((blockIdx.x >> 3)*2 + sub)*4 + w;
    const int g = l >> 4, i = l & 15;
    int beg = rowp[node], end = rowp[node+1];
    float rd = adst[node];
    float acc[8];
    #pragma unroll
    for(int k=0;k<8;k++) acc[k]=0.f;
    float dpart = 0.f;
    const char* hb = (const char*)hbuf + chunk*256 + 16*i;
    for(int base=beg; base<end; base+=64){
        int clen = min(64, end-base);
        unsigned soff = 0; float eereg = 0.f;
        if(l < clen){
            int s = colsrc[base + l];
            soff = (unsigned)s << 10;        // row byte offset (1024B rows)
            float e = asrc[s] + rd;
            e = (e > 0.f) ? e : 0.2f*e;
            eereg = expf(e);
            dpart += eereg;
        }
        int cpad = (clen + 3) & ~3;
        unsigned o0 = (unsigned)__shfl((int)soff, g);
        float w0 = __shfl(eereg, g);
        uint4 v0 = *(const uint4*)(hb + o0);
        #pragma unroll 1
        for(int j0=0; j0<cpad; j0+=4){
            uint4 nv; float nw = 0.f;
            const bool more = (j0+4 < cpad);
            if(more){
                unsigned no = (unsigned)__shfl((int)soff, j0+4+g);
                nw = __shfl(eereg, j0+4+g);
                nv = *(const uint4*)(hb + no);
            }
            FMA_MIX_LO(acc[0], v0.x, w0);  FMA_MIX_HI(acc[1], v0.x, w0);
            FMA_MIX_LO(acc[2], v0.y, w0);  FMA_MIX_HI(acc[3], v0.y, w0);
            FMA_MIX_LO(acc[4], v0.z, w0);  FMA_MIX_HI(acc[5], v0.z, w0);
            FMA_MIX_LO(acc[6], v0.w, w0);  FMA_MIX_HI(acc[7], v0.w, w0);
            if(more){ v0 = nv; w0 = nw; }
        }
    }
    #pragma unroll
    for(int k=0;k<8;k++){
        acc[k] += __shfl_xor(acc[k], 16);
        acc[k] += __shfl_xor(acc[k], 32);
    }
    #pragma unroll
    for(int off=1; off<64; off<<=1) dpart += __shfl_xor(dpart, off);
    float dn = dpart + 1e-16f;
    if(g == 0){
        const int f = chunk*128 + 8*i;
        float4 b0 = *(const float4*)(bias + f);
        float4 b1 = *(const float4*)(bias + f + 4);
        float bb[8] = {b0.x,b0.y,b0.z,b0.w, b1.x,b1.y,b1.z,b1.w};
        half8 o;
        #pragma unroll
        for(int k=0;k<8;k++)
            o[k] = (_Float16)fmaxf(acc[k]/dn + bb[k], 0.f);
        *(half8*)(oa + (size_t)node*INT_DIM + f) = o;
    }
}

// ---------------- single-pass fp16 MFMA GEMM, 8 waves (2x4), 128x128 tile, dbuf 2-phase ----------------
template<int FUSE>
__global__ __launch_bounds__(512, 4) void mfma16_gemm_kernel(
    const _Float16* __restrict__ A, int lda, int za,
    const _Float16* __restrict__ B, int ldb, int zb,
    const float* __restrict__ bias, _Float16* __restrict__ O,
    int ldc, int zc, int K, int gx)
{
    __shared__ _Float16 lA[2][128*32];   // 8 KB per buffer
    __shared__ _Float16 lB[2][128*32];
    const int tid  = threadIdx.x;
    const int lane = tid & 63;
    const int w    = tid >> 6;      // 0..7
    const int wm   = w >> 2;        // 0..1 (row half)
    const int wn   = w & 3;         // 0..3 (col quarter)
    const int z    = blockIdx.z;

    // XCD-bijective swizzle
    const int nwg = gridDim.x;
    const int q = nwg >> 3, r = nwg & 7;
    const int xcd = blockIdx.x & 7, idx = blockIdx.x >> 3;
    const int wgid = (xcd < r ? xcd*(q+1) : r*(q+1) + (xcd-r)*q) + idx;
    const int row0 = (wgid / gx) * 128, col0 = (wgid % gx) * 128;

    f32x4 acc[4][2];
    #pragma unroll
    for(int i=0;i<4;i++)
        #pragma unroll
        for(int j=0;j<2;j++) acc[i][j] = (f32x4){0.f,0.f,0.f,0.f};

    // staging: 512 lanes cover 128 rows x 4 slots of 16B; LDS slot written = tid&3
    const int rr1 = tid >> 2;                        // 0..127
    const int ss1 = (tid & 3) ^ ((rr1 >> 1) & 3);    // swizzled global slot
    const size_t aoff = (size_t)(row0 + rr1) * lda + (size_t)z*za + ss1 * 8;
    const size_t boff = (size_t)(col0 + rr1) * ldb + (size_t)z*zb + ss1 * 8;

    typedef __attribute__((address_space(3))) char lds_char;
    lds_char* dA = (lds_char*)(&lA[0][0]) + w*1024;
    lds_char* dB = (lds_char*)(&lB[0][0]) + w*1024;

    int arow[4], brow[2];
    const int slotx = ((lane >> 4) ^ ((lane >> 1) & 3)) << 4;
    #pragma unroll
    for(int i=0;i<4;i++)
        arow[i] = (wm*64 + i*16 + (lane & 15)) * 64 + slotx;
    #pragma unroll
    for(int j=0;j<2;j++)
        brow[j] = (wn*32 + j*16 + (lane & 15)) * 64 + slotx;

    #define GLDS(src, dst) __builtin_amdgcn_global_load_lds( \
        (__attribute__((address_space(1))) void*)(src), \
        (__attribute__((address_space(3))) void*)(dst), 16, 0, 0)
    GLDS(A + aoff, dA);
    GLDS(B + boff, dB);
    __syncthreads();

    #pragma unroll 1
    for(int k0 = 0, kb = 0; k0 < K; k0 += 32, kb ^= 1){
        if(k0 + 32 < K){
            const int nb = kb ^ 1;
            GLDS(A + aoff + k0 + 32, dA + nb*8192);
            GLDS(B + boff + k0 + 32, dB + nb*8192);
        }
        const char* pA = (const char*)(&lA[0][0]) + kb*8192;
        const char* pB = (const char*)(&lB[0][0]) + kb*8192;
        half8 af[4];
        #pragma unroll
        for(int i=0;i<4;i++) af[i] = *(const half8*)(pA + arow[i]);
        #pragma unroll
        for(int j=0;j<2;j++){
            half8 bf = *(const half8*)(pB + brow[j]);
            #pragma unroll
            for(int i=0;i<4;i++)
                acc[i][j] = __builtin_amdgcn_mfma_f32_16x16x32_f16(af[i], bf, acc[i][j], 0, 0, 0);
        }
        __syncthreads();
    }
    #undef GLDS

    // epilogue: C/D layout col=lane&15, row=(lane>>4)*4+reg
    #pragma unroll
    for(int i=0;i<4;i++){
        const int rr = row0 + wm*64 + i*16 + ((lane >> 4) << 2);
        #pragma unroll
        for(int j=0;j<2;j++){
            const int gc = z*zc + col0 + wn*32 + j*16 + (lane & 15);
            float b = FUSE ? bias[gc] : 0.f;
            #pragma unroll
            for(int rg=0;rg<4;rg++){
                float v = acc[i][j][rg];
                if(FUSE) v = fmaxf(v + b, 0.f);
                O[(size_t)(rr + rg) * ldc + gc] = (_Float16)v;
            }
        }
    }
}

// ---------------- alpha from fp16 h: H=8, C=128 ----------------
__global__ __launch_bounds__(128) void alpha16_h8_kernel(const _Float16* __restrict__ hbuf,
                                                         const float* __restrict__ a_src,
                                                         const float* __restrict__ a_dst,
                                                         float* __restrict__ asrc, float* __restrict__ adst){
    int node = blockIdx.x;
    int t = threadIdx.x;          // 128 threads; features 8t..8t+7, head t>>4
    half8 v = ((const half8*)(hbuf + (size_t)node*F1))[t];
    const float4* ap = (const float4*)(a_src + 8*t);
    const float4* dp = (const float4*)(a_dst + 8*t);
    float4 a0 = ap[0], a1 = ap[1];
    float4 d0 = dp[0], d1 = dp[1];
    float av[8] = {a0.x,a0.y,a0.z,a0.w, a1.x,a1.y,a1.z,a1.w};
    float dv[8] = {d0.x,d0.y,d0.z,d0.w, d1.x,d1.y,d1.z,d1.w};
    float ps = 0.f, pd = 0.f;
    #pragma unroll
    for(int k=0;k<8;k++){
        float f = (float)v[k];
        ps += f * av[k];
        pd += f * dv[k];
    }
    #pragma unroll
    for(int off=8; off; off>>=1){ ps += __shfl_down(ps, off); pd += __shfl_down(pd, off); }
    if((t & 15) == 0){
        asrc[(size_t)node*8 + (t>>4)] = ps;
        adst[(size_t)node*8 + (t>>4)] = pd;
    }
}

// ---------------- alpha from fp16 h: H=1, C=512 ----------------
__global__ __launch_bounds__(128) void alpha16_h1_kernel(const _Float16* __restrict__ hbuf,
                                                         const float* __restrict__ a_src,
                                                         const float* __restrict__ a_dst,
                                                         float* __restrict__ asrc, float* __restrict__ adst){
    int node = blockIdx.x;
    int t = threadIdx.x;          // 128 threads; features 4t..4t+3
    half4 v = ((const half4*)(hbuf + (size_t)node*INT_DIM))[t];
    float4 a = ((const float4*)a_src)[t];
    float4 d = ((const float4*)a_dst)[t];
    float ps = (float)v[0]*a.x + (float)v[1]*a.y + (float)v[2]*a.z + (float)v[3]*a.w;
    float pd = (float)v[0]*d.x + (float)v[1]*d.y + (float)v[2]*d.z + (float)v[3]*d.w;
    #pragma unroll
    for(int off=32; off; off>>=1){ ps += __shfl_down(ps, off); pd += __shfl_down(pd, off); }
    __shared__ float shs[2], shd[2];
    int wv = t >> 6;
    if((t & 63) == 0){ shs[wv] = ps; shd[wv] = pd; }
    __syncthreads();
    if(t == 0){
        asrc[node] = shs[0] + shs[1];
        adst[node] = shd[0] + shd[1];
    }
}

// ---------------- classifier: out[n,3] = h16[n,:512] @ Wc + bc ----------------
__global__ __launch_bounds__(256) void cls16_kernel(const _Float16* __restrict__ h, const float* __restrict__ Wc,
                                                    const float* __restrict__ bc, float* __restrict__ out, int n){
    int node = blockIdx.x*4 + (threadIdx.x >> 6);
    int lane = threadIdx.x & 63;
    if(node >= n) return;
    half8 v = ((const half8*)(h + (size_t)node*INT_DIM))[lane];  // features 8l..8l+7
    float s0=0.f, s1=0.f, s2=0.f;
    #pragma unroll
    for(int k=0;k<8;k++){
        float f = (float)v[k];
        const float* wr = Wc + (8*lane + k)*3;
        s0 += f * wr[0];
        s1 += f * wr[1];
        s2 += f * wr[2];
    }
    #pragma unroll
    for(int off=32; off; off>>=1){
        s0 += __shfl_down(s0, off);
        s1 += __shfl_down(s1, off);
        s2 += __shfl_down(s2, off);
    }
    if(lane==0){
        out[(size_t)node*3+0] = s0 + bc[0];
        out[(size_t)node*3+1] = s1 + bc[1];
        out[(size_t)node*3+2] = s2 + bc[2];
    }
}

extern "C" void kernel_launch(void* const* d_in, const int* in_sizes, int n_in,
                              void* d_out, int out_size, void* d_ws, size_t ws_size,
                              hipStream_t stream){
    const float* x      = (const float*)d_in[0];
    const int*   ei     = (const int*)d_in[1];
    const float* W1     = (const float*)d_in[2];
    const float* a_src1 = (const float*)d_in[3];
    const float* a_dst1 = (const float*)d_in[4];
    const float* b1     = (const float*)d_in[5];
    const float* W2     = (const float*)d_in[6];
    const float* a_src2 = (const float*)d_in[7];
    const float* a_dst2 = (const float*)d_in[8];
    const float* b2     = (const float*)d_in[9];
    const float* W3     = (const float*)d_in[10];
    const float* a_src3 = (const float*)d_in[11];
    const float* a_dst3 = (const float*)d_in[12];
    const float* b3     = (const float*)d_in[13];
    const float* Wl     = (const float*)d_in[14];
    const float* bl     = (const float*)d_in[15];
    const float* Wc     = (const float*)d_in[16];
    const float* bc     = (const float*)d_in[17];
    float* out = (float*)d_out;

    const int* src = ei;
    const int* dst = ei + EE;

    // workspace carve: two 41.4MB regions; hA/hB (fp16, 20.7MB each) use the lower halves,
    // weights + x16 live in regA's free upper half.
    char* p = (char*)d_ws;
    char* regA = p;  p += (size_t)MPAD*F1*4;
    char* regB = p;  p += (size_t)MPAD*F1*4;
    float* aw1  = (float*)p;  p += 16*IN_DIM*4;
    float* asrc = (float*)p;  p += (size_t)NN*HEADS*4;
    float* adst = (float*)p;  p += (size_t)NN*HEADS*4;
    int* cnt    = (int*)p;    p += NN*4;
    int* rowp   = (int*)p;    p += (NN+1)*4;
    int* cursor = (int*)p;    p += NN*4;
    int* colsrc = (int*)p;    p += EE*4;

    _Float16* hA = (_Float16*)regA;      // xa -> h2 -> h3 -> lin
    _Float16* hB = (_Float16*)regB;      // out1 -> out2 -> out3
    _Float16* up   = (_Float16*)(regA + (size_t)MPAD*F1*2);   // free upper half of regA
    _Float16* tW1  = up;                        // 1024*128
    _Float16* tW2  = tW1 + (size_t)F1*IN_DIM;   // 1024*1024
    _Float16* tW3  = tW2 + (size_t)F1*F1;       // 512*1024
    _Float16* tWl  = tW3 + (size_t)INT_DIM*F1;  // 512*512
    _Float16* x16  = tWl + (size_t)INT_DIM*INT_DIM;  // 10000*128

    // ---- fused prep (weights/x16/aw1/cnt-zero) + CSR build + alpha1 ----
    prep_kernel<<<3188, 256, 0, stream>>>(W1, W2, W3, Wl, x, a_src1, a_dst1,
                                          tW1, tW2, tW3, tWl, x16, aw1, cnt);
    count_alpha1_kernel<<<1250, 256, 0, stream>>>(dst, cnt, x, aw1, asrc, adst);
    scan_kernel<<<1, 1024, 0, stream>>>(cnt, rowp, cursor, NN);
    fill_kernel<<<(EE+255)/256, 256, 0, stream>>>(src, dst, EE, cursor, colsrc);

    // ---- Layer 1 (agg-first via linearity) ----
    agg1_kernel<<<NN/4, 256, 0, stream>>>(x16, asrc, adst, rowp, colsrc, hA);
    mfma16_gemm_kernel<1><<<dim3(MPAD/128, 1, HEADS), 512, 0, stream>>>(
        hA, F1, 128,  tW1, IN_DIM, 128*IN_DIM,
        b1, hB, F1, 128,  IN_DIM, 1);

    // ---- Layer 2 (project-first, fp16) ----
    mfma16_gemm_kernel<0><<<dim3((F1/128)*(MPAD/128), 1, 1), 512, 0, stream>>>(
        hB, F1, 0,  tW2, F1, 0,
        nullptr, hA, F1, 0,  F1, F1/128);
    alpha16_h8_kernel<<<NN, 128, 0, stream>>>(hA, a_src2, a_dst2, asrc, adst);
    agg2_kernel<<<(NN/4)*8, 256, 0, stream>>>(hA, asrc, adst, rowp, colsrc, b2, hB);

    // ---- Layer 3 (project-first, H=1, fp16) ----
    mfma16_gemm_kernel<0><<<dim3((INT_DIM/128)*(MPAD/128), 1, 1), 512, 0, stream>>>(
        hB, F1, 0,  tW3, F1, 0,
        nullptr, hA, INT_DIM, 0,  F1, INT_DIM/128);
    alpha16_h1_kernel<<<NN, 128, 0, stream>>>(hA, a_src3, a_dst3, asrc, adst);
    agg3_kernel<<<(NN/8)*8, 256, 0, stream>>>(hA, asrc, adst, rowp, colsrc, b3, hB);

    // ---- Linear: relu(out3 @ Wl + bl) -> hA fp16 [NN,512] ----
    mfma16_gemm_kernel<1><<<dim3((INT_DIM/128)*(MPAD/128), 1, 1), 512, 0, stream>>>(
        hB, INT_DIM, 0,  tWl, INT_DIM, 0,
        bl, hA, INT_DIM, 0,  INT_DIM, INT_DIM/128);

    // ---- Classifier ----
    cls16_kernel<<<(NN+3)/4, 256, 0, stream>>>(hA, Wc, bc, out, NN);
}